// Round 8
// baseline (1132.064 us; speedup 1.0000x reference)
//
#include <hip/hip_runtime.h>
#include <hip/hip_bf16.h>

// Windowed SDPA, B=1 H=16 S=4096 D=64, window +-128, temp 8.
// Outputs: out [16,4096,64] fp32, attn [16,4096,4096] fp32 (concatenated).
// Two dispatches:
//  zfill: maximal fill-clone. 256 blocks (1/CU), 256 threads, NO predication,
//         each block zeroes a contiguous 4.19MB slice of attn linearly.
//         Theory: streaming-store BW needs FEW long linear streams (rocclr
//         fill: 6.2 TB/s at 10% occupancy); our previous kernels ran 12-32
//         scattered write streams per CU -> ~3.3 TB/s.
//  wattn: R7 compute structure (TRB=64, fused online PV, unnorm band +
//         L2-hot fixup) with ALL zero stores removed. Serialized after zfill
//         so band overwrite is ordered.

typedef short bf16x8 __attribute__((ext_vector_type(8)));
typedef float f32x4  __attribute__((ext_vector_type(4)));
typedef unsigned int u32;
typedef unsigned short u16;

namespace {
constexpr int S = 4096, H = 16, Dh = 64, TRB = 64, HW = 128, NCH = 5;
constexpr int KP  = 72;                      // padded row stride (halves)
constexpr int NTILE = H * (S / TRB);         // 1024 compute blocks
}

__device__ __forceinline__ u16 f2bf(float x) {          // fp32 -> bf16 RNE
    u32 u = __float_as_uint(x);
    return (u16)((u + 0x7fffu + ((u >> 16) & 1u)) >> 16);
}
__device__ __forceinline__ float bf2f(u16 h) {
    return __uint_as_float(((u32)h) << 16);
}

// Raw workgroup barrier: LDS ordering only, no vmcnt drain.
__device__ __forceinline__ void bar_lds() {
    asm volatile("s_waitcnt lgkmcnt(0)" ::: "memory");
    __builtin_amdgcn_s_barrier();
    asm volatile("" ::: "memory");
}

// ---------------- zfill: 256 long linear streams, 1 block/CU --------------
__global__ __launch_bounds__(256)
void zfill(float* __restrict__ attn)
{
    constexpr size_t NF4     = (size_t)H * S * S / 4;   // 67,108,864 float4
    constexpr size_t PER_BLK = NF4 / 256;               // 262,144 float4
    f32x4* dst = (f32x4*)attn + (size_t)blockIdx.x * PER_BLK;
    const f32x4 z4 = {0.f, 0.f, 0.f, 0.f};
    for (size_t i = threadIdx.x; i < PER_BLK; i += 1024) {
        dst[i]       = z4;
        dst[i + 256] = z4;
        dst[i + 512] = z4;
        dst[i + 768] = z4;
    }
}

__global__ __launch_bounds__(256, 4)
void wattn(const float* __restrict__ q, const float* __restrict__ k,
           const float* __restrict__ v, float* __restrict__ out,
           float* __restrict__ attn)
{
    // LDS: kh[64][72] kl[64][72] vt[64][72] pc[64][72] = 36.9 KB -> 4 blk/CU
    __shared__ __align__(16) u16 hbuf[4 * 64 * KP];
    __shared__ float inv_row[TRB];
    u16* kh_ = hbuf;
    u16* kl_ = hbuf + 64 * KP;
    u16* vt_ = hbuf + 2 * 64 * KP;
    u16* pc_ = hbuf + 3 * 64 * KP;

    const int tid  = threadIdx.x;
    const int wave = tid >> 6, lane = tid & 63;
    const int g = lane >> 4, m = lane & 15;

    int bx = blockIdx.x;                                  // XCD-contiguous swizzle
    bx = (bx & 7) * (NTILE / 8) + (bx >> 3);
    const int h  = bx >> 6;
    const int r0 = (bx & 63) * TRB;
    const int c0 = max(0, r0 - HW);
    const int c1 = min(S - 1, r0 + TRB - 1 + HW);
    const int c0q = c0 >> 2;                              // band start, float4 units

    const float* qp = q + ((size_t)h * S + r0) * Dh;
    const float* kp = k + (size_t)h * S * Dh;
    const float* vp = v + (size_t)h * S * Dh;
    float* arow = attn + ((size_t)h * S + r0) * S;

    // ---------------- q A-fragments: wave owns rows r0+wave*16..+15 -------
    bf16x8 aqh[2], aql[2];
    #pragma unroll
    for (int ks = 0; ks < 2; ++ks) {
        const float* qsrc = qp + (wave * 16 + m) * Dh + ks * 32 + g * 8;
        float4 t0 = *(const float4*)(qsrc);
        float4 t1 = *(const float4*)(qsrc + 4);
        float xs[8] = {t0.x, t0.y, t0.z, t0.w, t1.x, t1.y, t1.z, t1.w};
        #pragma unroll
        for (int i = 0; i < 8; ++i) {
            u16 hi = f2bf(xs[i]);
            aqh[ks][i] = (short)hi;
            aql[ks][i] = (short)f2bf(xs[i] - bf2f(hi));
        }
    }

    // staging thread maps
    const int kcol = tid >> 2, kd = (tid & 3) * 16;       // k: row kcol, 16 d
    const int vj = tid & 63, vd = (tid >> 6) * 16;        // v: row vj, 16 d

    // prefetch chunk 0
    float4 rk[4], rv[4];
    {
        const float* src = kp + (size_t)min(c0 + kcol, S - 1) * Dh + kd;
        #pragma unroll
        for (int i4 = 0; i4 < 4; ++i4) rk[i4] = *(const float4*)(src + i4 * 4);
    }
    {
        const float* src = vp + (size_t)min(c0 + vj, S - 1) * Dh + vd;
        #pragma unroll
        for (int i4 = 0; i4 < 4; ++i4) rv[i4] = *(const float4*)(src + i4 * 4);
    }

    float rs[4] = {0.f, 0.f, 0.f, 0.f};
    f32x4 oacc[4] = {{0.f,0.f,0.f,0.f},{0.f,0.f,0.f,0.f},
                     {0.f,0.f,0.f,0.f},{0.f,0.f,0.f,0.f}};

    for (int cc = 0; cc < NCH; ++cc) {
        if (cc) bar_lds();               // prior PV ds-reads retired
        // ---- stage k hi/lo ----
        {
            u16* dh = kh_ + kcol * KP + kd;
            u16* dl = kl_ + kcol * KP + kd;
            #pragma unroll
            for (int i4 = 0; i4 < 4; ++i4) {
                float xs[4] = {rk[i4].x, rk[i4].y, rk[i4].z, rk[i4].w};
                #pragma unroll
                for (int i = 0; i < 4; ++i) {
                    u16 hi = f2bf(xs[i]);
                    dh[i4 * 4 + i] = hi;
                    dl[i4 * 4 + i] = f2bf(xs[i] - bf2f(hi));
                }
            }
        }
        // ---- stage v transposed ----
        #pragma unroll
        for (int i4 = 0; i4 < 4; ++i4) {
            float xs[4] = {rv[i4].x, rv[i4].y, rv[i4].z, rv[i4].w};
            #pragma unroll
            for (int i = 0; i < 4; ++i)
                vt_[(vd + i4 * 4 + i) * KP + vj] = f2bf(xs[i]);
        }
        // ---- prefetch next chunk ----
        if (cc + 1 < NCH) {
            const float* srck = kp + (size_t)min(c0 + (cc + 1) * 64 + kcol, S - 1) * Dh + kd;
            const float* srcv = vp + (size_t)min(c0 + (cc + 1) * 64 + vj,   S - 1) * Dh + vd;
            #pragma unroll
            for (int i4 = 0; i4 < 4; ++i4) {
                rk[i4] = *(const float4*)(srck + i4 * 4);
                rv[i4] = *(const float4*)(srcv + i4 * 4);
            }
        }
        bar_lds();                       // k/v tile visible
        // ---- QK: 4 col-subtiles x (2 ks x 3 mfma hi/lo) ----
        f32x4 acc[4] = {{0.f,0.f,0.f,0.f},{0.f,0.f,0.f,0.f},
                        {0.f,0.f,0.f,0.f},{0.f,0.f,0.f,0.f}};
        #pragma unroll
        for (int ci = 0; ci < 4; ++ci) {
            #pragma unroll
            for (int ks = 0; ks < 2; ++ks) {
                bf16x8 bh = *(const bf16x8*)(kh_ + (ci * 16 + m) * KP + ks * 32 + g * 8);
                bf16x8 bl = *(const bf16x8*)(kl_ + (ci * 16 + m) * KP + ks * 32 + g * 8);
                acc[ci] = __builtin_amdgcn_mfma_f32_16x16x32_bf16(aqh[ks], bh, acc[ci], 0, 0, 0);
                acc[ci] = __builtin_amdgcn_mfma_f32_16x16x32_bf16(aql[ks], bh, acc[ci], 0, 0, 0);
                acc[ci] = __builtin_amdgcn_mfma_f32_16x16x32_bf16(aqh[ks], bl, acc[ci], 0, 0, 0);
            }
        }
        // ---- exp + pc write + running row sums ----
        #pragma unroll
        for (int ci = 0; ci < 4; ++ci) {
            const int colg = c0 + cc * 64 + ci * 16 + m;
            #pragma unroll
            for (int w = 0; w < 4; ++w) {
                const int row = r0 + wave * 16 + g * 4 + w;
                const float l = acc[ci][w] * 0.125f;
                const bool ok = (colg >= row - HW) && (colg <= row + HW) && (colg <= c1);
                const float ev = ok ? __expf(l) : 0.f;
                rs[w] += ev;
                pc_[(wave * 16 + g * 4 + w) * KP + ci * 16 + m] = f2bf(ev);
            }
        }
        bar_lds();                       // pc/vt ready for PV + band store
        // ---- band store (unnormalized, cached: fixup re-reads from L2) ----
        {
            const int br = tid >> 2, bc = tid & 3;
            #pragma unroll
            for (int it = 0; it < 4; ++it) {
                const int c = bc + 4 * it;
                const int col4 = c0q + cc * 16 + c;
                if (col4 < S / 4) {
                    ushort4 hh = *(const ushort4*)(pc_ + br * KP + c * 4);
                    float4 val;
                    val.x = bf2f(hh.x); val.y = bf2f(hh.y);
                    val.z = bf2f(hh.z); val.w = bf2f(hh.w);
                    ((float4*)(arow + (size_t)br * S))[col4] = val;
                }
            }
        }
        // ---- PV online accumulate (unnormalized) ----
        #pragma unroll
        for (int di = 0; di < 4; ++di) {
            #pragma unroll
            for (int ks = 0; ks < 2; ++ks) {
                bf16x8 ap = *(const bf16x8*)(pc_ + (wave * 16 + m) * KP + ks * 32 + g * 8);
                bf16x8 bv = *(const bf16x8*)(vt_ + (di * 16 + m) * KP + ks * 32 + g * 8);
                oacc[di] = __builtin_amdgcn_mfma_f32_16x16x32_bf16(ap, bv, oacc[di], 0, 0, 0);
            }
        }
    }

    // ---------------- row sums -> inv (wave-local, butterfly over m) ------
    #pragma unroll
    for (int off = 1; off < 16; off <<= 1) {
        #pragma unroll
        for (int w = 0; w < 4; ++w) rs[w] += __shfl_xor(rs[w], off, 64);
    }
    float invw[4];
    #pragma unroll
    for (int w = 0; w < 4; ++w) invw[w] = 1.0f / rs[w];
    if (m == 0) {
        #pragma unroll
        for (int w = 0; w < 4; ++w) inv_row[wave * 16 + g * 4 + w] = invw[w];
    }

    // ---------------- out epilogue (rows wave*16+g*4+w, d = di*16+m) ------
    {
        float* ob = out + ((size_t)h * S + r0 + wave * 16) * Dh;
        #pragma unroll
        for (int di = 0; di < 4; ++di)
            #pragma unroll
            for (int w = 0; w < 4; ++w)
                ob[(g * 4 + w) * Dh + di * 16 + m] = oacc[di][w] * invw[w];
    }

    // ---------------- band fixup: rescale in place (L2-hot) ---------------
    asm volatile("s_waitcnt vmcnt(0)" ::: "memory");   // band stores in L2
    bar_lds();                                         // + inv_row visible
    #pragma unroll 4
    for (int it = 0; it < 20; ++it) {
        const int idx = tid + 256 * it;                // 64 rows x 80 float4
        const int r = idx / 80;
        const int c = idx - r * 80;
        const int col4 = c0q + c;
        if (col4 < S / 4) {
            float4* p = (float4*)(arow + (size_t)r * S) + col4;
            float4 t = *p;
            const float iv = inv_row[r];
            t.x *= iv; t.y *= iv; t.z *= iv; t.w *= iv;
            *p = t;
        }
    }
}

extern "C" void kernel_launch(void* const* d_in, const int* in_sizes, int n_in,
                              void* d_out, int out_size, void* d_ws, size_t ws_size,
                              hipStream_t stream) {
    const float* q = (const float*)d_in[0];
    const float* k = (const float*)d_in[1];
    const float* v = (const float*)d_in[2];
    float* out  = (float*)d_out;
    float* attn = out + (size_t)H * S * Dh;
    // zfill first (covers whole attn incl. band), wattn second overwrites the
    // band with values -- same-stream dispatches serialize, so this is ordered.
    zfill<<<dim3(256), dim3(256), 0, stream>>>(attn);
    wattn<<<dim3(NTILE), dim3(256), 0, stream>>>(q, k, v, out, attn);
}

// Round 9
// 1121.968 us; speedup vs baseline: 1.0090x; 1.0090x over previous
//
#include <hip/hip_runtime.h>
#include <hip/hip_bf16.h>

// Windowed SDPA, B=1 H=16 S=4096 D=64, window +-128, temp 8.
// Outputs: out [16,4096,64] fp32, attn [16,4096,4096] fp32 (concatenated).
// Two dispatches:
//  zfill: nontemporal linear zero of the WHOLE attn (1.07 GB), 2048 blocks x
//         contiguous 512KB chunks -> streams through L2 like rocclr fill.
//  wattn: TRB=64 compute; full P kept in LDS (pb[64][328], wave-private) so
//         the band is stored normalized ONCE in the tail (no fixup, no
//         mid-kernel vmcnt drain). Band overwrite of zfill's zeros is ordered
//         by same-stream serialization. All attn/out stores nontemporal.

typedef short bf16x8 __attribute__((ext_vector_type(8)));
typedef float f32x4  __attribute__((ext_vector_type(4)));
typedef unsigned int u32;
typedef unsigned short u16;

namespace {
constexpr int S = 4096, H = 16, Dh = 64, TRB = 64, HW = 128, NCH = 5;
constexpr int KP  = 72;                      // padded row stride (halves)
constexpr int PBW = 328;                     // pb row stride (halves)
constexpr int NTILE = H * (S / TRB);         // 1024 compute blocks
}

__device__ __forceinline__ u16 f2bf(float x) {          // fp32 -> bf16 RNE
    u32 u = __float_as_uint(x);
    return (u16)((u + 0x7fffu + ((u >> 16) & 1u)) >> 16);
}
__device__ __forceinline__ float bf2f(u16 h) {
    return __uint_as_float(((u32)h) << 16);
}

// Raw workgroup barrier: LDS ordering only, no vmcnt drain.
__device__ __forceinline__ void bar_lds() {
    asm volatile("s_waitcnt lgkmcnt(0)" ::: "memory");
    __builtin_amdgcn_s_barrier();
    asm volatile("" ::: "memory");
}

// ---------------- zfill: 2048 contiguous 512KB NT streams -----------------
__global__ __launch_bounds__(256)
void zfill(float* __restrict__ attn)
{
    constexpr size_t NF4 = (size_t)H * S * S / 4;       // 67,108,864 f32x4
    constexpr size_t PER = NF4 / 2048;                  // 32,768 f32x4 = 512KB
    f32x4* dst = (f32x4*)attn + (size_t)blockIdx.x * PER;
    const f32x4 z4 = {0.f, 0.f, 0.f, 0.f};
    for (size_t i = threadIdx.x; i < PER; i += 1024) {
        __builtin_nontemporal_store(z4, dst + i);
        __builtin_nontemporal_store(z4, dst + i + 256);
        __builtin_nontemporal_store(z4, dst + i + 512);
        __builtin_nontemporal_store(z4, dst + i + 768);
    }
}

__global__ __launch_bounds__(256, 2)
void wattn(const float* __restrict__ q, const float* __restrict__ k,
           const float* __restrict__ v, float* __restrict__ out,
           float* __restrict__ attn)
{
    // LDS: kh[64][72] kl[64][72] vt[64][72] (27.6KB) + pb[64][328] (42KB)
    __shared__ __align__(16) u16 hbuf[3 * 64 * KP];
    __shared__ __align__(16) u16 pbuf[64 * PBW];
    __shared__ float inv_row[TRB];
    u16* kh_ = hbuf;
    u16* kl_ = hbuf + 64 * KP;
    u16* vt_ = hbuf + 2 * 64 * KP;
    u16* pb_ = pbuf;

    const int tid  = threadIdx.x;
    const int wave = tid >> 6, lane = tid & 63;
    const int g = lane >> 4, m = lane & 15;

    int bx = blockIdx.x;                                  // XCD-contiguous swizzle
    bx = (bx & 7) * (NTILE / 8) + (bx >> 3);
    const int h  = bx >> 6;
    const int r0 = (bx & 63) * TRB;
    const int c0 = max(0, r0 - HW);
    const int c1 = min(S - 1, r0 + TRB - 1 + HW);
    const int c0q = c0 >> 2;                              // band start, float4 units

    const float* qp = q + ((size_t)h * S + r0) * Dh;
    const float* kp = k + (size_t)h * S * Dh;
    const float* vp = v + (size_t)h * S * Dh;
    float* arow = attn + ((size_t)h * S + r0) * S;

    // ---------------- q A-fragments: wave owns rows r0+wave*16..+15 -------
    bf16x8 aqh[2], aql[2];
    #pragma unroll
    for (int ks = 0; ks < 2; ++ks) {
        const float* qsrc = qp + (wave * 16 + m) * Dh + ks * 32 + g * 8;
        float4 t0 = *(const float4*)(qsrc);
        float4 t1 = *(const float4*)(qsrc + 4);
        float xs[8] = {t0.x, t0.y, t0.z, t0.w, t1.x, t1.y, t1.z, t1.w};
        #pragma unroll
        for (int i = 0; i < 8; ++i) {
            u16 hi = f2bf(xs[i]);
            aqh[ks][i] = (short)hi;
            aql[ks][i] = (short)f2bf(xs[i] - bf2f(hi));
        }
    }

    // staging thread maps
    const int kcol = tid >> 2, kd = (tid & 3) * 16;       // k: row kcol, 16 d
    const int vj = tid & 63, vd = (tid >> 6) * 16;        // v: row vj, 16 d

    // prefetch chunk 0
    float4 rk[4], rv[4];
    {
        const float* src = kp + (size_t)min(c0 + kcol, S - 1) * Dh + kd;
        #pragma unroll
        for (int i4 = 0; i4 < 4; ++i4) rk[i4] = *(const float4*)(src + i4 * 4);
    }
    {
        const float* src = vp + (size_t)min(c0 + vj, S - 1) * Dh + vd;
        #pragma unroll
        for (int i4 = 0; i4 < 4; ++i4) rv[i4] = *(const float4*)(src + i4 * 4);
    }

    float rs[4] = {0.f, 0.f, 0.f, 0.f};
    f32x4 oacc[4] = {{0.f,0.f,0.f,0.f},{0.f,0.f,0.f,0.f},
                     {0.f,0.f,0.f,0.f},{0.f,0.f,0.f,0.f}};

    for (int cc = 0; cc < NCH; ++cc) {
        if (cc) bar_lds();               // prior PV vt-reads retired
        // ---- stage k hi/lo ----
        {
            u16* dh = kh_ + kcol * KP + kd;
            u16* dl = kl_ + kcol * KP + kd;
            #pragma unroll
            for (int i4 = 0; i4 < 4; ++i4) {
                float xs[4] = {rk[i4].x, rk[i4].y, rk[i4].z, rk[i4].w};
                #pragma unroll
                for (int i = 0; i < 4; ++i) {
                    u16 hi = f2bf(xs[i]);
                    dh[i4 * 4 + i] = hi;
                    dl[i4 * 4 + i] = f2bf(xs[i] - bf2f(hi));
                }
            }
        }
        // ---- stage v transposed ----
        #pragma unroll
        for (int i4 = 0; i4 < 4; ++i4) {
            float xs[4] = {rv[i4].x, rv[i4].y, rv[i4].z, rv[i4].w};
            #pragma unroll
            for (int i = 0; i < 4; ++i)
                vt_[(vd + i4 * 4 + i) * KP + vj] = f2bf(xs[i]);
        }
        // ---- prefetch next chunk ----
        if (cc + 1 < NCH) {
            const float* srck = kp + (size_t)min(c0 + (cc + 1) * 64 + kcol, S - 1) * Dh + kd;
            const float* srcv = vp + (size_t)min(c0 + (cc + 1) * 64 + vj,   S - 1) * Dh + vd;
            #pragma unroll
            for (int i4 = 0; i4 < 4; ++i4) {
                rk[i4] = *(const float4*)(srck + i4 * 4);
                rv[i4] = *(const float4*)(srcv + i4 * 4);
            }
        }
        bar_lds();                       // k/v tile visible
        // ---- QK: 4 col-subtiles x (2 ks x 3 mfma hi/lo) ----
        f32x4 acc[4] = {{0.f,0.f,0.f,0.f},{0.f,0.f,0.f,0.f},
                        {0.f,0.f,0.f,0.f},{0.f,0.f,0.f,0.f}};
        #pragma unroll
        for (int ci = 0; ci < 4; ++ci) {
            #pragma unroll
            for (int ks = 0; ks < 2; ++ks) {
                bf16x8 bh = *(const bf16x8*)(kh_ + (ci * 16 + m) * KP + ks * 32 + g * 8);
                bf16x8 bl = *(const bf16x8*)(kl_ + (ci * 16 + m) * KP + ks * 32 + g * 8);
                acc[ci] = __builtin_amdgcn_mfma_f32_16x16x32_bf16(aqh[ks], bh, acc[ci], 0, 0, 0);
                acc[ci] = __builtin_amdgcn_mfma_f32_16x16x32_bf16(aql[ks], bh, acc[ci], 0, 0, 0);
                acc[ci] = __builtin_amdgcn_mfma_f32_16x16x32_bf16(aqh[ks], bl, acc[ci], 0, 0, 0);
            }
        }
        // ---- exp + pb write (wave-private rows) + running row sums ----
        #pragma unroll
        for (int ci = 0; ci < 4; ++ci) {
            const int colg = c0 + cc * 64 + ci * 16 + m;
            #pragma unroll
            for (int w = 0; w < 4; ++w) {
                const int row = r0 + wave * 16 + g * 4 + w;
                const float l = acc[ci][w] * 0.125f;
                const bool ok = (colg >= row - HW) && (colg <= row + HW) && (colg <= c1);
                const float ev = ok ? __expf(l) : 0.f;
                rs[w] += ev;
                pb_[(wave * 16 + g * 4 + w) * PBW + cc * 64 + ci * 16 + m] = f2bf(ev);
            }
        }
        // ---- PV online accumulate (unnormalized; pb rows are wave-own) ----
        #pragma unroll
        for (int di = 0; di < 4; ++di) {
            #pragma unroll
            for (int ks = 0; ks < 2; ++ks) {
                bf16x8 ap = *(const bf16x8*)(pb_ + (wave * 16 + m) * PBW + cc * 64 + ks * 32 + g * 8);
                bf16x8 bv = *(const bf16x8*)(vt_ + (di * 16 + m) * KP + ks * 32 + g * 8);
                oacc[di] = __builtin_amdgcn_mfma_f32_16x16x32_bf16(ap, bv, oacc[di], 0, 0, 0);
            }
        }
    }

    // ---------------- row sums -> inv (wave-local, butterfly over m) ------
    #pragma unroll
    for (int off = 1; off < 16; off <<= 1) {
        #pragma unroll
        for (int w = 0; w < 4; ++w) rs[w] += __shfl_xor(rs[w], off, 64);
    }
    float invw[4];
    #pragma unroll
    for (int w = 0; w < 4; ++w) invw[w] = 1.0f / rs[w];
    if (m == 0) {
        #pragma unroll
        for (int w = 0; w < 4; ++w) inv_row[wave * 16 + g * 4 + w] = invw[w];
    }

    // ---------------- out epilogue (rows wave*16+g*4+w, d = di*16+m) ------
    {
        float* ob = out + ((size_t)h * S + r0 + wave * 16) * Dh;
        #pragma unroll
        for (int di = 0; di < 4; ++di)
            #pragma unroll
            for (int w = 0; w < 4; ++w)
                __builtin_nontemporal_store(oacc[di][w] * invw[w],
                                            ob + (g * 4 + w) * Dh + di * 16 + m);
    }

    bar_lds();                           // pb (all waves) + inv_row visible

    // ---------------- band store: 64 rows x 80 f32x4, normalized, NT ------
    for (int it = 0; it < 20; ++it) {
        const int idx = tid + 256 * it;                // 5120 = 64*80 slots
        const int r = idx / 80;
        const int c = idx - r * 80;
        const int col4 = c0q + c;
        if (col4 < S / 4) {
            ushort4 hh = *(const ushort4*)(pb_ + r * PBW + c * 4);
            const float inv = inv_row[r];
            f32x4 val;
            val[0] = bf2f(hh.x) * inv; val[1] = bf2f(hh.y) * inv;
            val[2] = bf2f(hh.z) * inv; val[3] = bf2f(hh.w) * inv;
            __builtin_nontemporal_store(val, (f32x4*)(arow + (size_t)r * S) + col4);
        }
    }
}

extern "C" void kernel_launch(void* const* d_in, const int* in_sizes, int n_in,
                              void* d_out, int out_size, void* d_ws, size_t ws_size,
                              hipStream_t stream) {
    const float* q = (const float*)d_in[0];
    const float* k = (const float*)d_in[1];
    const float* v = (const float*)d_in[2];
    float* out  = (float*)d_out;
    float* attn = out + (size_t)H * S * Dh;
    // zfill covers the whole attn (incl. band); wattn overwrites the band.
    // Same-stream dispatches serialize -> ordered.
    zfill<<<dim3(2048), dim3(256), 0, stream>>>(attn);
    wattn<<<dim3(NTILE), dim3(256), 0, stream>>>(q, k, v, out, attn);
}

// Round 10
// 1114.820 us; speedup vs baseline: 1.0155x; 1.0064x over previous
//
#include <hip/hip_runtime.h>
#include <hip/hip_bf16.h>

// Windowed SDPA, B=1 H=16 S=4096 D=64, window +-128, temp 8.
// Outputs: out [16,4096,64] fp32, attn [16,4096,4096] fp32 (concatenated).
// R10 = R9 with ALL nontemporal stores reverted to plain stores (strict A/B).
//  zfill: plain linear zero of the WHOLE attn (1.07 GB), 2048 blocks x
//         contiguous 512KB chunks (L2 write-combining, like rocclr fill).
//  wattn: TRB=64 compute; full P kept in LDS (pb[64][328], wave-private) so
//         the band is stored normalized ONCE in the tail (no fixup, no
//         mid-kernel vmcnt drain). Band overwrite of zfill's zeros is ordered
//         by same-stream serialization.

typedef short bf16x8 __attribute__((ext_vector_type(8)));
typedef float f32x4  __attribute__((ext_vector_type(4)));
typedef unsigned int u32;
typedef unsigned short u16;

namespace {
constexpr int S = 4096, H = 16, Dh = 64, TRB = 64, HW = 128, NCH = 5;
constexpr int KP  = 72;                      // padded row stride (halves)
constexpr int PBW = 328;                     // pb row stride (halves)
constexpr int NTILE = H * (S / TRB);         // 1024 compute blocks
}

__device__ __forceinline__ u16 f2bf(float x) {          // fp32 -> bf16 RNE
    u32 u = __float_as_uint(x);
    return (u16)((u + 0x7fffu + ((u >> 16) & 1u)) >> 16);
}
__device__ __forceinline__ float bf2f(u16 h) {
    return __uint_as_float(((u32)h) << 16);
}

// Raw workgroup barrier: LDS ordering only, no vmcnt drain.
__device__ __forceinline__ void bar_lds() {
    asm volatile("s_waitcnt lgkmcnt(0)" ::: "memory");
    __builtin_amdgcn_s_barrier();
    asm volatile("" ::: "memory");
}

// ---------------- zfill: 2048 contiguous 512KB plain streams --------------
__global__ __launch_bounds__(256)
void zfill(float* __restrict__ attn)
{
    constexpr size_t NF4 = (size_t)H * S * S / 4;       // 67,108,864 f32x4
    constexpr size_t PER = NF4 / 2048;                  // 32,768 f32x4 = 512KB
    f32x4* dst = (f32x4*)attn + (size_t)blockIdx.x * PER;
    const f32x4 z4 = {0.f, 0.f, 0.f, 0.f};
    for (size_t i = threadIdx.x; i < PER; i += 1024) {
        dst[i]       = z4;
        dst[i + 256] = z4;
        dst[i + 512] = z4;
        dst[i + 768] = z4;
    }
}

__global__ __launch_bounds__(256, 2)
void wattn(const float* __restrict__ q, const float* __restrict__ k,
           const float* __restrict__ v, float* __restrict__ out,
           float* __restrict__ attn)
{
    // LDS: kh[64][72] kl[64][72] vt[64][72] (27.6KB) + pb[64][328] (42KB)
    __shared__ __align__(16) u16 hbuf[3 * 64 * KP];
    __shared__ __align__(16) u16 pbuf[64 * PBW];
    __shared__ float inv_row[TRB];
    u16* kh_ = hbuf;
    u16* kl_ = hbuf + 64 * KP;
    u16* vt_ = hbuf + 2 * 64 * KP;
    u16* pb_ = pbuf;

    const int tid  = threadIdx.x;
    const int wave = tid >> 6, lane = tid & 63;
    const int g = lane >> 4, m = lane & 15;

    int bx = blockIdx.x;                                  // XCD-contiguous swizzle
    bx = (bx & 7) * (NTILE / 8) + (bx >> 3);
    const int h  = bx >> 6;
    const int r0 = (bx & 63) * TRB;
    const int c0 = max(0, r0 - HW);
    const int c1 = min(S - 1, r0 + TRB - 1 + HW);
    const int c0q = c0 >> 2;                              // band start, float4 units

    const float* qp = q + ((size_t)h * S + r0) * Dh;
    const float* kp = k + (size_t)h * S * Dh;
    const float* vp = v + (size_t)h * S * Dh;
    float* arow = attn + ((size_t)h * S + r0) * S;

    // ---------------- q A-fragments: wave owns rows r0+wave*16..+15 -------
    bf16x8 aqh[2], aql[2];
    #pragma unroll
    for (int ks = 0; ks < 2; ++ks) {
        const float* qsrc = qp + (wave * 16 + m) * Dh + ks * 32 + g * 8;
        float4 t0 = *(const float4*)(qsrc);
        float4 t1 = *(const float4*)(qsrc + 4);
        float xs[8] = {t0.x, t0.y, t0.z, t0.w, t1.x, t1.y, t1.z, t1.w};
        #pragma unroll
        for (int i = 0; i < 8; ++i) {
            u16 hi = f2bf(xs[i]);
            aqh[ks][i] = (short)hi;
            aql[ks][i] = (short)f2bf(xs[i] - bf2f(hi));
        }
    }

    // staging thread maps
    const int kcol = tid >> 2, kd = (tid & 3) * 16;       // k: row kcol, 16 d
    const int vj = tid & 63, vd = (tid >> 6) * 16;        // v: row vj, 16 d

    // prefetch chunk 0
    float4 rk[4], rv[4];
    {
        const float* src = kp + (size_t)min(c0 + kcol, S - 1) * Dh + kd;
        #pragma unroll
        for (int i4 = 0; i4 < 4; ++i4) rk[i4] = *(const float4*)(src + i4 * 4);
    }
    {
        const float* src = vp + (size_t)min(c0 + vj, S - 1) * Dh + vd;
        #pragma unroll
        for (int i4 = 0; i4 < 4; ++i4) rv[i4] = *(const float4*)(src + i4 * 4);
    }

    float rs[4] = {0.f, 0.f, 0.f, 0.f};
    f32x4 oacc[4] = {{0.f,0.f,0.f,0.f},{0.f,0.f,0.f,0.f},
                     {0.f,0.f,0.f,0.f},{0.f,0.f,0.f,0.f}};

    for (int cc = 0; cc < NCH; ++cc) {
        if (cc) bar_lds();               // prior PV vt-reads retired
        // ---- stage k hi/lo ----
        {
            u16* dh = kh_ + kcol * KP + kd;
            u16* dl = kl_ + kcol * KP + kd;
            #pragma unroll
            for (int i4 = 0; i4 < 4; ++i4) {
                float xs[4] = {rk[i4].x, rk[i4].y, rk[i4].z, rk[i4].w};
                #pragma unroll
                for (int i = 0; i < 4; ++i) {
                    u16 hi = f2bf(xs[i]);
                    dh[i4 * 4 + i] = hi;
                    dl[i4 * 4 + i] = f2bf(xs[i] - bf2f(hi));
                }
            }
        }
        // ---- stage v transposed ----
        #pragma unroll
        for (int i4 = 0; i4 < 4; ++i4) {
            float xs[4] = {rv[i4].x, rv[i4].y, rv[i4].z, rv[i4].w};
            #pragma unroll
            for (int i = 0; i < 4; ++i)
                vt_[(vd + i4 * 4 + i) * KP + vj] = f2bf(xs[i]);
        }
        // ---- prefetch next chunk ----
        if (cc + 1 < NCH) {
            const float* srck = kp + (size_t)min(c0 + (cc + 1) * 64 + kcol, S - 1) * Dh + kd;
            const float* srcv = vp + (size_t)min(c0 + (cc + 1) * 64 + vj,   S - 1) * Dh + vd;
            #pragma unroll
            for (int i4 = 0; i4 < 4; ++i4) {
                rk[i4] = *(const float4*)(srck + i4 * 4);
                rv[i4] = *(const float4*)(srcv + i4 * 4);
            }
        }
        bar_lds();                       // k/v tile visible
        // ---- QK: 4 col-subtiles x (2 ks x 3 mfma hi/lo) ----
        f32x4 acc[4] = {{0.f,0.f,0.f,0.f},{0.f,0.f,0.f,0.f},
                        {0.f,0.f,0.f,0.f},{0.f,0.f,0.f,0.f}};
        #pragma unroll
        for (int ci = 0; ci < 4; ++ci) {
            #pragma unroll
            for (int ks = 0; ks < 2; ++ks) {
                bf16x8 bh = *(const bf16x8*)(kh_ + (ci * 16 + m) * KP + ks * 32 + g * 8);
                bf16x8 bl = *(const bf16x8*)(kl_ + (ci * 16 + m) * KP + ks * 32 + g * 8);
                acc[ci] = __builtin_amdgcn_mfma_f32_16x16x32_bf16(aqh[ks], bh, acc[ci], 0, 0, 0);
                acc[ci] = __builtin_amdgcn_mfma_f32_16x16x32_bf16(aql[ks], bh, acc[ci], 0, 0, 0);
                acc[ci] = __builtin_amdgcn_mfma_f32_16x16x32_bf16(aqh[ks], bl, acc[ci], 0, 0, 0);
            }
        }
        // ---- exp + pb write (wave-private rows) + running row sums ----
        #pragma unroll
        for (int ci = 0; ci < 4; ++ci) {
            const int colg = c0 + cc * 64 + ci * 16 + m;
            #pragma unroll
            for (int w = 0; w < 4; ++w) {
                const int row = r0 + wave * 16 + g * 4 + w;
                const float l = acc[ci][w] * 0.125f;
                const bool ok = (colg >= row - HW) && (colg <= row + HW) && (colg <= c1);
                const float ev = ok ? __expf(l) : 0.f;
                rs[w] += ev;
                pb_[(wave * 16 + g * 4 + w) * PBW + cc * 64 + ci * 16 + m] = f2bf(ev);
            }
        }
        // ---- PV online accumulate (unnormalized; pb rows are wave-own) ----
        #pragma unroll
        for (int di = 0; di < 4; ++di) {
            #pragma unroll
            for (int ks = 0; ks < 2; ++ks) {
                bf16x8 ap = *(const bf16x8*)(pb_ + (wave * 16 + m) * PBW + cc * 64 + ks * 32 + g * 8);
                bf16x8 bv = *(const bf16x8*)(vt_ + (di * 16 + m) * KP + ks * 32 + g * 8);
                oacc[di] = __builtin_amdgcn_mfma_f32_16x16x32_bf16(ap, bv, oacc[di], 0, 0, 0);
            }
        }
    }

    // ---------------- row sums -> inv (wave-local, butterfly over m) ------
    #pragma unroll
    for (int off = 1; off < 16; off <<= 1) {
        #pragma unroll
        for (int w = 0; w < 4; ++w) rs[w] += __shfl_xor(rs[w], off, 64);
    }
    float invw[4];
    #pragma unroll
    for (int w = 0; w < 4; ++w) invw[w] = 1.0f / rs[w];
    if (m == 0) {
        #pragma unroll
        for (int w = 0; w < 4; ++w) inv_row[wave * 16 + g * 4 + w] = invw[w];
    }

    // ---------------- out epilogue (rows wave*16+g*4+w, d = di*16+m) ------
    {
        float* ob = out + ((size_t)h * S + r0 + wave * 16) * Dh;
        #pragma unroll
        for (int di = 0; di < 4; ++di)
            #pragma unroll
            for (int w = 0; w < 4; ++w)
                ob[(g * 4 + w) * Dh + di * 16 + m] = oacc[di][w] * invw[w];
    }

    bar_lds();                           // pb (all waves) + inv_row visible

    // ---------------- band store: 64 rows x 80 f32x4, normalized ----------
    for (int it = 0; it < 20; ++it) {
        const int idx = tid + 256 * it;                // 5120 = 64*80 slots
        const int r = idx / 80;
        const int c = idx - r * 80;
        const int col4 = c0q + c;
        if (col4 < S / 4) {
            ushort4 hh = *(const ushort4*)(pb_ + r * PBW + c * 4);
            const float inv = inv_row[r];
            f32x4 val;
            val[0] = bf2f(hh.x) * inv; val[1] = bf2f(hh.y) * inv;
            val[2] = bf2f(hh.z) * inv; val[3] = bf2f(hh.w) * inv;
            *((f32x4*)(arow + (size_t)r * S) + col4) = val;
        }
    }
}

extern "C" void kernel_launch(void* const* d_in, const int* in_sizes, int n_in,
                              void* d_out, int out_size, void* d_ws, size_t ws_size,
                              hipStream_t stream) {
    const float* q = (const float*)d_in[0];
    const float* k = (const float*)d_in[1];
    const float* v = (const float*)d_in[2];
    float* out  = (float*)d_out;
    float* attn = out + (size_t)H * S * Dh;
    // zfill covers the whole attn (incl. band); wattn overwrites the band.
    // Same-stream dispatches serialize -> ordered.
    zfill<<<dim3(2048), dim3(256), 0, stream>>>(attn);
    wattn<<<dim3(NTILE), dim3(256), 0, stream>>>(q, k, v, out, attn);
}

// Round 11
// 1096.632 us; speedup vs baseline: 1.0323x; 1.0166x over previous
//
#include <hip/hip_runtime.h>
#include <hip/hip_bf16.h>

// Windowed SDPA, B=1 H=16 S=4096 D=64, window +-128, temp 8.
// Outputs: out [16,4096,64] fp32, attn [16,4096,4096] fp32 (concatenated).
// Persistent-block design: 512 blocks (2/CU), each owns 2 consecutive tiles
// (TRB=64 rows) = one contiguous 2.1 MB attn region. Per tile: compute band
// (bf16 hi/lo QK + online PV, P in LDS, normalized once) then sweep the full
// 64 rows (zeros + band) as ONE long linear store stream. Store streams are
// rocclr-fill-shaped (512 long contiguous streams); tile t's stores drain
// under tile t+1's compute (load-before-store + lgkmcnt-only barriers);
// no separate zfill pass, no fixup RMW, no mid-kernel vmcnt(0).

typedef short bf16x8 __attribute__((ext_vector_type(8)));
typedef float f32x4  __attribute__((ext_vector_type(4)));
typedef unsigned int u32;
typedef unsigned short u16;

namespace {
constexpr int S = 4096, H = 16, Dh = 64, TRB = 64, HW = 128, NCH = 5;
constexpr int KP  = 72;                      // padded row stride (halves)
constexpr int PBW = 328;                     // pb row stride (halves)
constexpr int NTILE  = H * (S / TRB);        // 1024 tiles
constexpr int NT_PER = 2;                    // tiles per block
constexpr int NBLK   = NTILE / NT_PER;       // 512 blocks
}

__device__ __forceinline__ u16 f2bf(float x) {          // fp32 -> bf16 RNE
    u32 u = __float_as_uint(x);
    return (u16)((u + 0x7fffu + ((u >> 16) & 1u)) >> 16);
}
__device__ __forceinline__ float bf2f(u16 h) {
    return __uint_as_float(((u32)h) << 16);
}

// Raw workgroup barrier: LDS ordering only, no vmcnt drain.
__device__ __forceinline__ void bar_lds() {
    asm volatile("s_waitcnt lgkmcnt(0)" ::: "memory");
    __builtin_amdgcn_s_barrier();
    asm volatile("" ::: "memory");
}

__global__ __launch_bounds__(256, 2)
void wattn(const float* __restrict__ q, const float* __restrict__ k,
           const float* __restrict__ v, float* __restrict__ out,
           float* __restrict__ attn)
{
    // LDS: kh[64][72] kl[64][72] vt[64][72] (27.6KB) + pb[64][328] (42KB)
    __shared__ __align__(16) u16 hbuf[3 * 64 * KP];
    __shared__ __align__(16) u16 pbuf[64 * PBW];
    __shared__ float inv_row[TRB];
    u16* kh_ = hbuf;
    u16* kl_ = hbuf + 64 * KP;
    u16* vt_ = hbuf + 2 * 64 * KP;
    u16* pb_ = pbuf;

    const int tid  = threadIdx.x;
    const int wave = tid >> 6, lane = tid & 63;
    const int g = lane >> 4, m = lane & 15;

    int bx = blockIdx.x;                                  // XCD-contiguous swizzle
    bx = (bx & 7) * (NBLK / 8) + (bx >> 3);               // 512 % 8 == 0: bijective
    const int t0 = bx * NT_PER;                           // first tile (h-major)

    // staging thread maps
    const int kcol = tid >> 2, kd = (tid & 3) * 16;       // k: row kcol, 16 d
    const int vj = tid & 63, vd = (tid >> 6) * 16;        // v: row vj, 16 d

    // ---------------- prefetch chunk 0 of tile t0 --------------------------
    float4 rk[4], rv[4];
    {
        const int h = t0 >> 6, r0 = (t0 & 63) * TRB;
        const int c0 = max(0, r0 - HW);
        const float* kpp = k + (size_t)h * S * Dh;
        const float* vpp = v + (size_t)h * S * Dh;
        const float* srck = kpp + (size_t)min(c0 + kcol, S - 1) * Dh + kd;
        const float* srcv = vpp + (size_t)min(c0 + vj,   S - 1) * Dh + vd;
        #pragma unroll
        for (int i4 = 0; i4 < 4; ++i4) {
            rk[i4] = *(const float4*)(srck + i4 * 4);
            rv[i4] = *(const float4*)(srcv + i4 * 4);
        }
    }

    for (int tt = 0; tt < NT_PER; ++tt) {
        const int t  = t0 + tt;
        const int h  = t >> 6;
        const int r0 = (t & 63) * TRB;
        const int c0 = max(0, r0 - HW);
        const int c1 = min(S - 1, r0 + TRB - 1 + HW);
        const int c0q = c0 >> 2;                          // band start, f32x4 units

        const float* qp = q + ((size_t)h * S + r0) * Dh;
        float* arow = attn + ((size_t)h * S + r0) * S;

        // ---- q A-fragments: wave owns rows r0+wave*16..+15 ----
        bf16x8 aqh[2], aql[2];
        #pragma unroll
        for (int ks = 0; ks < 2; ++ks) {
            const float* qsrc = qp + (wave * 16 + m) * Dh + ks * 32 + g * 8;
            float4 q0 = *(const float4*)(qsrc);
            float4 q1 = *(const float4*)(qsrc + 4);
            float xs[8] = {q0.x, q0.y, q0.z, q0.w, q1.x, q1.y, q1.z, q1.w};
            #pragma unroll
            for (int i = 0; i < 8; ++i) {
                u16 hi = f2bf(xs[i]);
                aqh[ks][i] = (short)hi;
                aql[ks][i] = (short)f2bf(xs[i] - bf2f(hi));
            }
        }

        float rs[4] = {0.f, 0.f, 0.f, 0.f};
        f32x4 oacc[4] = {{0.f,0.f,0.f,0.f},{0.f,0.f,0.f,0.f},
                         {0.f,0.f,0.f,0.f},{0.f,0.f,0.f,0.f}};

        for (int cc = 0; cc < NCH; ++cc) {
            if (cc | tt) bar_lds();      // prior PV vt-reads / prev-tile LDS retired
            // ---- stage k hi/lo ----
            {
                u16* dh = kh_ + kcol * KP + kd;
                u16* dl = kl_ + kcol * KP + kd;
                #pragma unroll
                for (int i4 = 0; i4 < 4; ++i4) {
                    float xs[4] = {rk[i4].x, rk[i4].y, rk[i4].z, rk[i4].w};
                    #pragma unroll
                    for (int i = 0; i < 4; ++i) {
                        u16 hi = f2bf(xs[i]);
                        dh[i4 * 4 + i] = hi;
                        dl[i4 * 4 + i] = f2bf(xs[i] - bf2f(hi));
                    }
                }
            }
            // ---- stage v transposed ----
            #pragma unroll
            for (int i4 = 0; i4 < 4; ++i4) {
                float xs[4] = {rv[i4].x, rv[i4].y, rv[i4].z, rv[i4].w};
                #pragma unroll
                for (int i = 0; i < 4; ++i)
                    vt_[(vd + i4 * 4 + i) * KP + vj] = f2bf(xs[i]);
            }
            // ---- prefetch: next chunk of this tile, or chunk 0 of next tile
            if (cc + 1 < NCH) {
                const float* kpp = k + (size_t)h * S * Dh;
                const float* vpp = v + (size_t)h * S * Dh;
                const float* srck = kpp + (size_t)min(c0 + (cc + 1) * 64 + kcol, S - 1) * Dh + kd;
                const float* srcv = vpp + (size_t)min(c0 + (cc + 1) * 64 + vj,   S - 1) * Dh + vd;
                #pragma unroll
                for (int i4 = 0; i4 < 4; ++i4) {
                    rk[i4] = *(const float4*)(srck + i4 * 4);
                    rv[i4] = *(const float4*)(srcv + i4 * 4);
                }
            } else if (tt + 1 < NT_PER) {
                const int tn = t + 1, hn = tn >> 6, r0n = (tn & 63) * TRB;
                const int c0n = max(0, r0n - HW);
                const float* kpn = k + (size_t)hn * S * Dh;
                const float* vpn = v + (size_t)hn * S * Dh;
                const float* srck = kpn + (size_t)min(c0n + kcol, S - 1) * Dh + kd;
                const float* srcv = vpn + (size_t)min(c0n + vj,   S - 1) * Dh + vd;
                #pragma unroll
                for (int i4 = 0; i4 < 4; ++i4) {
                    rk[i4] = *(const float4*)(srck + i4 * 4);
                    rv[i4] = *(const float4*)(srcv + i4 * 4);
                }
            }
            bar_lds();                   // k/v tile visible
            // ---- QK: 4 col-subtiles x (2 ks x 3 mfma hi/lo) ----
            f32x4 acc[4] = {{0.f,0.f,0.f,0.f},{0.f,0.f,0.f,0.f},
                            {0.f,0.f,0.f,0.f},{0.f,0.f,0.f,0.f}};
            #pragma unroll
            for (int ci = 0; ci < 4; ++ci) {
                #pragma unroll
                for (int ks = 0; ks < 2; ++ks) {
                    bf16x8 bh = *(const bf16x8*)(kh_ + (ci * 16 + m) * KP + ks * 32 + g * 8);
                    bf16x8 bl = *(const bf16x8*)(kl_ + (ci * 16 + m) * KP + ks * 32 + g * 8);
                    acc[ci] = __builtin_amdgcn_mfma_f32_16x16x32_bf16(aqh[ks], bh, acc[ci], 0, 0, 0);
                    acc[ci] = __builtin_amdgcn_mfma_f32_16x16x32_bf16(aql[ks], bh, acc[ci], 0, 0, 0);
                    acc[ci] = __builtin_amdgcn_mfma_f32_16x16x32_bf16(aqh[ks], bl, acc[ci], 0, 0, 0);
                }
            }
            // ---- exp + pb write (wave-private rows) + running row sums ----
            #pragma unroll
            for (int ci = 0; ci < 4; ++ci) {
                const int colg = c0 + cc * 64 + ci * 16 + m;
                #pragma unroll
                for (int w = 0; w < 4; ++w) {
                    const int row = r0 + wave * 16 + g * 4 + w;
                    const float l = acc[ci][w] * 0.125f;
                    const bool ok = (colg >= row - HW) && (colg <= row + HW) && (colg <= c1);
                    const float ev = ok ? __expf(l) : 0.f;
                    rs[w] += ev;
                    pb_[(wave * 16 + g * 4 + w) * PBW + cc * 64 + ci * 16 + m] = f2bf(ev);
                }
            }
            // ---- PV online accumulate (pb rows are wave-own, no barrier) ----
            #pragma unroll
            for (int di = 0; di < 4; ++di) {
                #pragma unroll
                for (int ks = 0; ks < 2; ++ks) {
                    bf16x8 ap = *(const bf16x8*)(pb_ + (wave * 16 + m) * PBW + cc * 64 + ks * 32 + g * 8);
                    bf16x8 bv = *(const bf16x8*)(vt_ + (di * 16 + m) * KP + ks * 32 + g * 8);
                    oacc[di] = __builtin_amdgcn_mfma_f32_16x16x32_bf16(ap, bv, oacc[di], 0, 0, 0);
                }
            }
        }

        // ---- row sums -> inv (wave-local, butterfly over m) ----
        #pragma unroll
        for (int off = 1; off < 16; off <<= 1) {
            #pragma unroll
            for (int w = 0; w < 4; ++w) rs[w] += __shfl_xor(rs[w], off, 64);
        }
        float invw[4];
        #pragma unroll
        for (int w = 0; w < 4; ++w) invw[w] = 1.0f / rs[w];
        if (m == 0) {
            #pragma unroll
            for (int w = 0; w < 4; ++w) inv_row[wave * 16 + g * 4 + w] = invw[w];
        }

        // ---- out epilogue (rows wave*16+g*4+w, d = di*16+m) ----
        {
            float* ob = out + ((size_t)h * S + r0 + wave * 16) * Dh;
            #pragma unroll
            for (int di = 0; di < 4; ++di)
                #pragma unroll
                for (int w = 0; w < 4; ++w)
                    ob[(g * 4 + w) * Dh + di * 16 + m] = oacc[di][w] * invw[w];
        }

        bar_lds();                       // pb (all waves) + inv_row visible

        // ---- full-row sweep: 64 rows x 16KB contiguous (zeros + band) ----
        // One long linear stream per tile; next tile's chunk-0 loads were
        // issued BEFORE these stores (FIFO -> loads retire first).
        for (int r = 0; r < TRB; ++r) {
            const float inv = inv_row[r];
            f32x4* dst = (f32x4*)(arow + (size_t)r * S);
            #pragma unroll
            for (int k4 = 0; k4 < 4; ++k4) {
                const int c4 = tid + 256 * k4;
                const int o4 = c4 - c0q;
                f32x4 val = {0.f, 0.f, 0.f, 0.f};
                if ((unsigned)o4 < 80u) {
                    ushort4 hh = *(const ushort4*)(pb_ + r * PBW + o4 * 4);
                    val[0] = bf2f(hh.x) * inv; val[1] = bf2f(hh.y) * inv;
                    val[2] = bf2f(hh.z) * inv; val[3] = bf2f(hh.w) * inv;
                }
                dst[c4] = val;
            }
        }
        // pb reuse by next tile is ordered by its first bar_lds (all waves'
        // sweep LDS-reads retire at that barrier's lgkmcnt(0)).
    }
}

extern "C" void kernel_launch(void* const* d_in, const int* in_sizes, int n_in,
                              void* d_out, int out_size, void* d_ws, size_t ws_size,
                              hipStream_t stream) {
    const float* q = (const float*)d_in[0];
    const float* k = (const float*)d_in[1];
    const float* v = (const float*)d_in[2];
    float* out  = (float*)d_out;
    float* attn = out + (size_t)H * S * Dh;
    wattn<<<dim3(NBLK), dim3(256), 0, stream>>>(q, k, v, out, attn);
}